// Round 3
// baseline (1525.258 us; speedup 1.0000x reference)
//
#include <hip/hip_runtime.h>

#define N_NODES 100000
#define N_EDGES 1250000
#define D 64
#define NPB 256                 // nodes per bucket (dst >> 8)
#define NB  391                 // ceil(N_NODES / NPB)
#define NPAD2 (NB * NPB)        // 100096

// ---------------- bucket histogram: 391 hot counters ----------------
__global__ __launch_bounds__(256) void bucket_hist_kernel(const int* __restrict__ dst,
                                                          int* __restrict__ bhist) {
    int e = blockIdx.x * 256 + threadIdx.x;
    if (e < N_EDGES) atomicAdd(&bhist[dst[e] >> 8], 1);
}

// ---------------- scan 391 bucket counts -> offsets + cursors ----------------
__global__ __launch_bounds__(512) void bucket_scan_kernel(const int* __restrict__ bhist,
                                                          int* __restrict__ boffs,
                                                          int* __restrict__ gcursor) {
    __shared__ int lds[512];
    int t = threadIdx.x;
    int v = (t < NB) ? bhist[t] : 0;
    int inc = v;
    lds[t] = inc;
    __syncthreads();
    for (int off = 1; off < 512; off <<= 1) {
        int y = (t >= off) ? lds[t - off] : 0;
        __syncthreads();
        inc += y;
        lds[t] = inc;
        __syncthreads();
    }
    int exc = inc - v;
    if (t < NB) { boffs[t] = exc; gcursor[t] = exc; }
    if (t == NB - 1) boffs[NB] = exc + v;
}

// ---------------- place edges into bucket runs, packed (src<<8)|dstlocal ----------------
__global__ __launch_bounds__(256) void bucket_place_kernel(const int* __restrict__ src,
                                                           const int* __restrict__ dst,
                                                           int* __restrict__ gcursor,
                                                           unsigned int* __restrict__ packed) {
    int e = blockIdx.x * 256 + threadIdx.x;
    if (e < N_EDGES) {
        int d = dst[e];
        int b = d >> 8;
        int pos = atomicAdd(&gcursor[b], 1);
        packed[pos] = ((unsigned)src[e] << 8) | (unsigned)(d & 255);   // src < 2^17
    }
}

// ---------------- exact degree via per-bucket LDS histogram -> norm ----------------
__global__ __launch_bounds__(256) void degnorm_kernel(const unsigned int* __restrict__ packed,
                                                      const int* __restrict__ boffs,
                                                      float* __restrict__ norm) {
    __shared__ int degl[NPB];
    int b = blockIdx.x, t = threadIdx.x;
    degl[t] = 0;
    __syncthreads();
    int beg = boffs[b], end = boffs[b + 1];
    for (int j = beg + t; j < end; j += 256)
        atomicAdd(&degl[packed[j] & 255], 1);
    __syncthreads();
    int n = b * NPB + t;
    if (n < N_NODES) {
        int c = degl[t];
        norm[n] = rsqrtf((float)(c < 1 ? 1 : c));
    }
}

// ---------------- aggregate: one block per bucket, LDS float atomics ----------------
// h[n] = norm[n] * sum feat[s]*norm[s]  -> d_out (coalesced write)
__global__ __launch_bounds__(512) void agg_kernel(const float* __restrict__ feat,
                                                  const unsigned int* __restrict__ packed,
                                                  const int* __restrict__ boffs,
                                                  const float* __restrict__ norm,
                                                  float* __restrict__ out) {
    __shared__ float agg[NPB * D];   // exactly 64 KB
    int t = threadIdx.x, b = blockIdx.x;
    float4* az = (float4*)agg;
    #pragma unroll
    for (int i = 0; i < 8; ++i) az[t + i * 512] = make_float4(0.f, 0.f, 0.f, 0.f);
    __syncthreads();

    int lane = t & 63, w = t >> 6;           // 8 waves
    int beg = boffs[b], len = boffs[b + 1] - beg;
    int j  = beg + (len * w) / 8;
    int j1 = beg + (len * (w + 1)) / 8;

    for (; j + 3 < j1; j += 4) {             // 4-wide ILP on the latency-bound gathers
        unsigned p0 = packed[j], p1 = packed[j + 1], p2 = packed[j + 2], p3 = packed[j + 3];
        int s0 = p0 >> 8, s1 = p1 >> 8, s2 = p2 >> 8, s3 = p3 >> 8;
        float f0 = feat[(size_t)s0 * D + lane] * norm[s0];
        float f1 = feat[(size_t)s1 * D + lane] * norm[s1];
        float f2 = feat[(size_t)s2 * D + lane] * norm[s2];
        float f3 = feat[(size_t)s3 * D + lane] * norm[s3];
        atomicAdd(&agg[(p0 & 255) * D + lane], f0);
        atomicAdd(&agg[(p1 & 255) * D + lane], f1);
        atomicAdd(&agg[(p2 & 255) * D + lane], f2);
        atomicAdd(&agg[(p3 & 255) * D + lane], f3);
    }
    for (; j < j1; ++j) {
        unsigned p = packed[j];
        int s = p >> 8;
        atomicAdd(&agg[(p & 255) * D + lane], feat[(size_t)s * D + lane] * norm[s]);
    }
    __syncthreads();

    #pragma unroll
    for (int i = 0; i < 32; ++i) {
        int idx = t + i * 512;               // 0..16383
        int nl = idx >> 6;
        int n = b * NPB + nl;
        if (n < N_NODES)
            out[(size_t)n * D + (idx & 63)] = agg[idx] * norm[n];
    }
}

// ---------------- GEMM: out = h @ W^T + bias, in-place on d_out ----------------
#define GPAD 68
__global__ __launch_bounds__(256) void gemm64_kernel(const float* __restrict__ weight,
                                                     const float* __restrict__ bias,
                                                     float* __restrict__ io) {
    __shared__ float Ht[D * GPAD];   // Ht[k][n]
    __shared__ float Wt[D * GPAD];   // Wt[k][d]
    int tid = threadIdx.x;
    int n0 = blockIdx.x * 64;
    int c = tid & 63;
    int r4 = tid >> 6;

    for (int dd = r4; dd < D; dd += 4)
        Wt[c * GPAD + dd] = weight[dd * D + c];
    for (int nl = r4; nl < 64; nl += 4) {
        int n = n0 + nl;
        Ht[c * GPAD + nl] = (n < N_NODES) ? io[(size_t)n * D + c] : 0.f;
    }
    __syncthreads();

    int tx = tid & 15, ty = tid >> 4;
    float acc[4][4] = {};
    #pragma unroll 8
    for (int k = 0; k < D; ++k) {
        float4 a = *(const float4*)&Ht[k * GPAD + ty * 4];
        float4 b = *(const float4*)&Wt[k * GPAD + tx * 4];
        acc[0][0] += a.x * b.x; acc[0][1] += a.x * b.y; acc[0][2] += a.x * b.z; acc[0][3] += a.x * b.w;
        acc[1][0] += a.y * b.x; acc[1][1] += a.y * b.y; acc[1][2] += a.y * b.z; acc[1][3] += a.y * b.w;
        acc[2][0] += a.z * b.x; acc[2][1] += a.z * b.y; acc[2][2] += a.z * b.z; acc[2][3] += a.z * b.w;
        acc[3][0] += a.w * b.x; acc[3][1] += a.w * b.y; acc[3][2] += a.w * b.z; acc[3][3] += a.w * b.w;
    }

    float4 bv = *(const float4*)&bias[tx * 4];
    #pragma unroll
    for (int i = 0; i < 4; ++i) {
        int n = n0 + ty * 4 + i;
        if (n < N_NODES) {
            *(float4*)&io[(size_t)n * D + tx * 4] =
                make_float4(acc[i][0] + bv.x, acc[i][1] + bv.y,
                            acc[i][2] + bv.z, acc[i][3] + bv.w);
        }
    }
}

extern "C" void kernel_launch(void* const* d_in, const int* in_sizes, int n_in,
                              void* d_out, int out_size, void* d_ws, size_t ws_size,
                              hipStream_t stream) {
    const float* feat   = (const float*)d_in[0];
    const int*   src    = (const int*)d_in[1];
    const int*   dst    = (const int*)d_in[2];
    const float* weight = (const float*)d_in[3];
    const float* bias   = (const float*)d_in[4];
    float* out = (float*)d_out;

    // workspace layout (4-byte units)
    int* w = (int*)d_ws;
    int*      bhist   = w;                       // [NB]
    int*      boffs   = w + NB;                  // [NB+1]
    int*      gcursor = w + 2 * NB + 1;          // [NB]
    float*    norm    = (float*)(w + 3 * NB + 1);        // [NPAD2]
    unsigned* packed  = (unsigned*)(w + 3 * NB + 1 + NPAD2);  // [N_EDGES]

    hipMemsetAsync(bhist, 0, NB * sizeof(int), stream);

    bucket_hist_kernel <<<(N_EDGES + 255) / 256, 256, 0, stream>>>(dst, bhist);
    bucket_scan_kernel <<<1, 512, 0, stream>>>(bhist, boffs, gcursor);
    bucket_place_kernel<<<(N_EDGES + 255) / 256, 256, 0, stream>>>(src, dst, gcursor, packed);
    degnorm_kernel     <<<NB, 256, 0, stream>>>(packed, boffs, norm);
    agg_kernel         <<<NB, 512, 0, stream>>>(feat, packed, boffs, norm, out);
    gemm64_kernel      <<<(N_NODES + 63) / 64, 256, 0, stream>>>(weight, bias, out);
}

// Round 4
// 210.372 us; speedup vs baseline: 7.2503x; 7.2503x over previous
//
#include <hip/hip_runtime.h>

#define N_NODES 100000
#define N_EDGES 1250000
#define D 64
#define NPB 256                  // nodes per coarse bucket (dst >> 8)
#define NB  391                  // ceil(N_NODES / NPB)
#define NPAD2 (NB * NPB)         // 100096
#define EPT 16                   // edges per thread in hist/place
#define EPB (256 * EPT)          // 4096 edges per block
#define NBLK ((N_EDGES + EPB - 1) / EPB)   // 306

// ---------------- coarse histogram: LDS first, 391 global adds per block ----------------
__global__ __launch_bounds__(256) void hist_kernel(const int* __restrict__ dst,
                                                   int* __restrict__ bhist) {
    __shared__ int h[NB];
    int t = threadIdx.x;
    for (int i = t; i < NB; i += 256) h[i] = 0;
    __syncthreads();
    int base = blockIdx.x * EPB;
    #pragma unroll
    for (int i = 0; i < EPT; ++i) {
        int e = base + t + i * 256;
        if (e < N_EDGES) atomicAdd(&h[dst[e] >> 8], 1);
    }
    __syncthreads();
    for (int i = t; i < NB; i += 256)
        if (h[i]) atomicAdd(&bhist[i], h[i]);
}

// ---------------- scan 391 bucket counts -> boffs + gcursor ----------------
__global__ __launch_bounds__(512) void bucket_scan_kernel(const int* __restrict__ bhist,
                                                          int* __restrict__ boffs,
                                                          int* __restrict__ gcursor) {
    __shared__ int lds[512];
    int t = threadIdx.x;
    int v = (t < NB) ? bhist[t] : 0;
    int inc = v;
    lds[t] = inc;
    __syncthreads();
    for (int off = 1; off < 512; off <<= 1) {
        int y = (t >= off) ? lds[t - off] : 0;
        __syncthreads();
        inc += y;
        lds[t] = inc;
        __syncthreads();
    }
    int exc = inc - v;
    if (t < NB) { boffs[t] = exc; gcursor[t] = exc; }
    if (t == NB - 1) boffs[NB] = exc + v;
}

// ---------------- place: block-level range reservation + LDS cursors ----------------
__global__ __launch_bounds__(256) void place_kernel(const int* __restrict__ src,
                                                    const int* __restrict__ dst,
                                                    int* __restrict__ gcursor,
                                                    unsigned int* __restrict__ packed) {
    __shared__ int h[NB];
    __shared__ int cur[NB];
    int t = threadIdx.x;
    for (int i = t; i < NB; i += 256) h[i] = 0;
    __syncthreads();
    int base = blockIdx.x * EPB;
    int d[EPT];
    #pragma unroll
    for (int i = 0; i < EPT; ++i) {
        int e = base + t + i * 256;
        d[i] = (e < N_EDGES) ? dst[e] : -1;
        if (d[i] >= 0) atomicAdd(&h[d[i] >> 8], 1);
    }
    __syncthreads();
    for (int i = t; i < NB; i += 256)
        cur[i] = h[i] ? atomicAdd(&gcursor[i], h[i]) : 0;   // reserve block's range
    __syncthreads();
    #pragma unroll
    for (int i = 0; i < EPT; ++i) {
        if (d[i] >= 0) {
            int e = base + t + i * 256;
            int pos = atomicAdd(&cur[d[i] >> 8], 1);
            packed[pos] = ((unsigned)src[e] << 8) | (unsigned)(d[i] & 255);
        }
    }
}

// ---------------- refine: per-bucket exact CSR (offs, ssorted) + norm ----------------
__global__ __launch_bounds__(256) void refine_kernel(const unsigned int* __restrict__ packed,
                                                     const int* __restrict__ boffs,
                                                     int* __restrict__ ssorted,
                                                     int* __restrict__ offs,
                                                     float* __restrict__ norm) {
    __shared__ int h[NPB];
    __shared__ int sc[NPB];
    __shared__ int cur[NPB];
    int b = blockIdx.x, t = threadIdx.x;
    int beg = boffs[b], end = boffs[b + 1];
    h[t] = 0;
    __syncthreads();
    for (int j = beg + t; j < end; j += 256)
        atomicAdd(&h[packed[j] & 255], 1);
    __syncthreads();
    int v = h[t], inc = v;
    sc[t] = inc;
    __syncthreads();
    for (int off = 1; off < 256; off <<= 1) {
        int y = (t >= off) ? sc[t - off] : 0;
        __syncthreads();
        inc += y;
        sc[t] = inc;
        __syncthreads();
    }
    int exc = inc - v;
    cur[t] = beg + exc;
    int n = b * NPB + t;
    offs[n] = beg + exc;                  // offs[100000] lands here correctly (= N_EDGES)
    if (n < N_NODES) norm[n] = rsqrtf((float)(v < 1 ? 1 : v));
    __syncthreads();
    for (int j = beg + t; j < end; j += 256) {
        unsigned p = packed[j];
        int pos = atomicAdd(&cur[p & 255], 1);
        ssorted[pos] = (int)(p >> 8);
    }
}

// ---------------- gather: one wave per node, float4, 4 edges per load instr ----------------
// lane = (q = edge slot 0..3) * 16 + (m = column quarter 0..15)
__global__ __launch_bounds__(256) void gather_kernel(const float* __restrict__ feat,
                                                     const int* __restrict__ ssorted,
                                                     const int* __restrict__ offs,
                                                     const float* __restrict__ norm,
                                                     float* __restrict__ out) {
    int n = blockIdx.x * 4 + (threadIdx.x >> 6);
    int lane = threadIdx.x & 63;
    if (n >= N_NODES) return;
    int beg = offs[n], end = offs[n + 1];
    int q = lane >> 4, m = lane & 15;
    float4 acc = make_float4(0.f, 0.f, 0.f, 0.f);
    int j = beg;
    for (; j + 16 <= end; j += 16) {       // 4 independent row-loads in flight
        #pragma unroll
        for (int g = 0; g < 4; ++g) {
            int s = ssorted[j + 4 * g + q];
            float4 f = *(const float4*)&feat[(size_t)s * D + m * 4];
            float ns = norm[s];
            acc.x += f.x * ns; acc.y += f.y * ns; acc.z += f.z * ns; acc.w += f.w * ns;
        }
    }
    for (; j + 4 <= end; j += 4) {
        int s = ssorted[j + q];
        float4 f = *(const float4*)&feat[(size_t)s * D + m * 4];
        float ns = norm[s];
        acc.x += f.x * ns; acc.y += f.y * ns; acc.z += f.z * ns; acc.w += f.w * ns;
    }
    if (j + q < end) {                      // tail (<4 edges), slot q takes edge j+q
        int s = ssorted[j + q];
        float4 f = *(const float4*)&feat[(size_t)s * D + m * 4];
        float ns = norm[s];
        acc.x += f.x * ns; acc.y += f.y * ns; acc.z += f.z * ns; acc.w += f.w * ns;
    }
    // combine the 4 edge slots (lane ^ 16, lane ^ 32)
    #pragma unroll
    for (int mask = 16; mask <= 32; mask <<= 1) {
        acc.x += __shfl_xor(acc.x, mask);
        acc.y += __shfl_xor(acc.y, mask);
        acc.z += __shfl_xor(acc.z, mask);
        acc.w += __shfl_xor(acc.w, mask);
    }
    if (q == 0) {
        float nn = norm[n];
        *(float4*)&out[(size_t)n * D + m * 4] =
            make_float4(acc.x * nn, acc.y * nn, acc.z * nn, acc.w * nn);
    }
}

// ---------------- GEMM: out = h @ W^T + bias, in-place on d_out ----------------
#define GPAD 68
__global__ __launch_bounds__(256) void gemm64_kernel(const float* __restrict__ weight,
                                                     const float* __restrict__ bias,
                                                     float* __restrict__ io) {
    __shared__ float Ht[D * GPAD];   // Ht[k][n]
    __shared__ float Wt[D * GPAD];   // Wt[k][d]
    int tid = threadIdx.x;
    int n0 = blockIdx.x * 64;
    int c = tid & 63;
    int r4 = tid >> 6;

    for (int dd = r4; dd < D; dd += 4)
        Wt[c * GPAD + dd] = weight[dd * D + c];
    for (int nl = r4; nl < 64; nl += 4) {
        int n = n0 + nl;
        Ht[c * GPAD + nl] = (n < N_NODES) ? io[(size_t)n * D + c] : 0.f;
    }
    __syncthreads();

    int tx = tid & 15, ty = tid >> 4;
    float acc[4][4] = {};
    #pragma unroll 8
    for (int k = 0; k < D; ++k) {
        float4 a = *(const float4*)&Ht[k * GPAD + ty * 4];
        float4 b = *(const float4*)&Wt[k * GPAD + tx * 4];
        acc[0][0] += a.x * b.x; acc[0][1] += a.x * b.y; acc[0][2] += a.x * b.z; acc[0][3] += a.x * b.w;
        acc[1][0] += a.y * b.x; acc[1][1] += a.y * b.y; acc[1][2] += a.y * b.z; acc[1][3] += a.y * b.w;
        acc[2][0] += a.z * b.x; acc[2][1] += a.z * b.y; acc[2][2] += a.z * b.z; acc[2][3] += a.z * b.w;
        acc[3][0] += a.w * b.x; acc[3][1] += a.w * b.y; acc[3][2] += a.w * b.z; acc[3][3] += a.w * b.w;
    }

    float4 bv = *(const float4*)&bias[tx * 4];
    #pragma unroll
    for (int i = 0; i < 4; ++i) {
        int n = n0 + ty * 4 + i;
        if (n < N_NODES) {
            *(float4*)&io[(size_t)n * D + tx * 4] =
                make_float4(acc[i][0] + bv.x, acc[i][1] + bv.y,
                            acc[i][2] + bv.z, acc[i][3] + bv.w);
        }
    }
}

extern "C" void kernel_launch(void* const* d_in, const int* in_sizes, int n_in,
                              void* d_out, int out_size, void* d_ws, size_t ws_size,
                              hipStream_t stream) {
    const float* feat   = (const float*)d_in[0];
    const int*   src    = (const int*)d_in[1];
    const int*   dst    = (const int*)d_in[2];
    const float* weight = (const float*)d_in[3];
    const float* bias   = (const float*)d_in[4];
    float* out = (float*)d_out;

    // workspace layout (4-byte units), total ~10.8 MB
    int* w = (int*)d_ws;
    int*      bhist   = w;                           // [NB]
    int*      boffs   = bhist + NB;                  // [NB+1]
    int*      gcursor = boffs + NB + 1;              // [NB]
    int*      offs    = gcursor + NB;                // [NPAD2]
    float*    norm    = (float*)(offs + NPAD2);      // [NPAD2]
    unsigned* packed  = (unsigned*)(norm + NPAD2);   // [N_EDGES]
    int*      ssorted = (int*)(packed + N_EDGES);    // [N_EDGES]

    hipMemsetAsync(bhist, 0, NB * sizeof(int), stream);

    hist_kernel       <<<NBLK, 256, 0, stream>>>(dst, bhist);
    bucket_scan_kernel<<<1, 512, 0, stream>>>(bhist, boffs, gcursor);
    place_kernel      <<<NBLK, 256, 0, stream>>>(src, dst, gcursor, packed);
    refine_kernel     <<<NB, 256, 0, stream>>>(packed, boffs, ssorted, offs, norm);
    gather_kernel     <<<(N_NODES + 3) / 4, 256, 0, stream>>>(feat, ssorted, offs, norm, out);
    gemm64_kernel     <<<(N_NODES + 63) / 64, 256, 0, stream>>>(weight, bias, out);
}